// Round 4
// baseline (345.415 us; speedup 1.0000x reference)
//
#include <hip/hip_runtime.h>
#include <cstdint>
#include <cstddef>

// ---------------------------------------------------------------------------
// Adaptive log-softmax NLL. bf16 MFMA GEMMs fused with online logsumexp.
// R4: head GEMM -> triple-buffered counted-vmcnt pipeline (raw s_barrier,
// vmcnt(6) once per K-tile, setprio around MFMA, T1 bijective XCD swizzle,
// T2 LDS swizzle); merged single-pass (M,S) shfl epilogue everywhere.
// ---------------------------------------------------------------------------

typedef unsigned short u16;
typedef __attribute__((ext_vector_type(8))) __bf16 bf16x8;
typedef __attribute__((ext_vector_type(8))) u16 u16x8;
typedef __attribute__((ext_vector_type(4))) float f32x4;

#define AS1 __attribute__((address_space(1)))
#define AS3 __attribute__((address_space(3)))

struct MS { float m, s; };

__device__ __forceinline__ u16 f2bf(float f){
  union { float f; unsigned u; } v; v.f = f;
  unsigned r = v.u + 0x7fffu + ((v.u >> 16) & 1u);  // RNE
  return (u16)(r >> 16);
}
__device__ __forceinline__ float bf2f(u16 x){
  union { unsigned u; float f; } v; v.u = ((unsigned)x) << 16;
  return v.f;
}
__device__ __forceinline__ void glds16(const void* g, void* l){
  __builtin_amdgcn_global_load_lds((AS1 unsigned*)(uintptr_t)g,
                                   (AS3 unsigned*)(unsigned)(uintptr_t)l, 16, 0, 0);
}
__device__ __forceinline__ void lse_merge(float& m, float& s, float m2, float s2){
  float M = fmaxf(m, m2);
  s = s * __expf(m - M) + s2 * __expf(m2 - M);
  m = M;
}

// ---------------- hidden f32 -> bf16 (+ init cnt and tgt_rel) ----------------
__global__ void k_cvt_hidden(const float* __restrict__ h, u16* __restrict__ a0,
                             int* __restrict__ cnt, int* __restrict__ trel){
  int g = blockIdx.x * 256 + threadIdx.x;
  if (g < 4096) trel[g] = -1;          // tr0..tr3, 1024 each, contiguous
  if (g < 4) cnt[g] = 0;
  int i = g * 8;
  f32x4 v0 = *(const f32x4*)(h + i);
  f32x4 v1 = *(const f32x4*)(h + i + 4);
  u16x8 o;
  o[0]=f2bf(v0.x); o[1]=f2bf(v0.y); o[2]=f2bf(v0.z); o[3]=f2bf(v0.w);
  o[4]=f2bf(v1.x); o[5]=f2bf(v1.y); o[6]=f2bf(v1.z); o[7]=f2bf(v1.w);
  *(u16x8*)(a0 + i) = o;
}

// ---------------- bucket compaction ----------------
__global__ void k_compact(const int* __restrict__ tgt, int* __restrict__ cnt,
                          int* __restrict__ idx1, int* __restrict__ idx2,
                          int* __restrict__ idx3, int* __restrict__ pos,
                          int* __restrict__ tr0, int* __restrict__ tr1,
                          int* __restrict__ tr2, int* __restrict__ tr3){
  int n = blockIdx.x * 256 + threadIdx.x;
  int t = tgt[n];
  int p = 0;
  tr0[n] = (t < 20000) ? t : -1;
  if (t >= 20000){
    int b = (t < 60000) ? 0 : (t < 180000 ? 1 : 2);
    p = atomicAdd(&cnt[b], 1);
    if (b == 0){ idx1[p] = n; tr1[p] = t - 20000; }
    else if (b == 1){ idx2[p] = n; tr2[p] = t - 60000; }
    else { idx3[p] = n; tr3[p] = t - 180000; }
  }
  pos[n] = p;
}

// ---------------- gather compacted tail-A rows ----------------
__global__ void k_gather(const int* __restrict__ cnt,
                         const int* __restrict__ idx1, const int* __restrict__ idx2,
                         const int* __restrict__ idx3,
                         const u16* __restrict__ A1, const u16* __restrict__ A2,
                         const u16* __restrict__ A3,
                         u16* __restrict__ A1c, u16* __restrict__ A2c,
                         u16* __restrict__ A3c){
  int u = blockIdx.x * 256 + threadIdx.x;
  const u16* src; u16* dst;
  if (u < 32768){
    int r = u >> 5, c = u & 31;
    if (r >= cnt[0]) return;
    src = A1 + (size_t)idx1[r] * 256 + c * 8;
    dst = A1c + (size_t)r * 256 + c * 8;
  } else if (u < 40960){
    int v = u - 32768; int r = v >> 3, c = v & 7;
    if (r >= cnt[1]) return;
    src = A2 + (size_t)idx2[r] * 64 + c * 8;
    dst = A2c + (size_t)r * 64 + c * 8;
  } else {
    int v = u - 40960; int r = v >> 2, c = v & 3;
    if (r >= cnt[2]) return;
    src = A3 + (size_t)idx3[r] * 32 + c * 8;
    dst = A3c + (size_t)r * 32 + c * 8;
  }
  *(u16x8*)dst = *(const u16x8*)src;
}

// ---------------- multi-job W [K][N] f32 -> BT [nrows][Kpad] bf16 ----------
struct TJob { const float* W; u16* BT; int K, N, Kpad, nrows, nx, base; };
struct TJobs { TJob j[8]; int nj; };

__global__ void k_transpose_multi(TJobs jobs){
  int id = blockIdx.x;
  int ji = 0;
  #pragma unroll
  for (int i = 1; i < 8; ++i)
    if (i < jobs.nj && id >= jobs.j[i].base) ji = i;
  TJob jb = jobs.j[ji];
  int local = id - jb.base;
  int bx = local % jb.nx;
  int by = local / jb.nx;

  __shared__ float t[64][65];
  const int n0 = bx * 64;
  const int k0 = by * 64;
  const bool al = (jb.N & 3) == 0;
  for (int i = threadIdx.x; i < 64*16; i += 256){
    int r = i >> 4, c4 = (i & 15) * 4;
    int k = k0 + r, n = n0 + c4;
    f32x4 v; v.x=0.f; v.y=0.f; v.z=0.f; v.w=0.f;
    if (k < jb.K){
      if (al && n + 3 < jb.N) v = *(const f32x4*)(jb.W + (size_t)k * jb.N + n);
      else { for (int q = 0; q < 4; ++q) if (n + q < jb.N) v[q] = jb.W[(size_t)k * jb.N + n + q]; }
    }
    t[r][c4] = v.x; t[r][c4+1] = v.y; t[r][c4+2] = v.z; t[r][c4+3] = v.w;
  }
  __syncthreads();
  for (int i = threadIdx.x; i < 64*8; i += 256){
    int rn = i >> 3, c8 = (i & 7) * 8;
    if (k0 + c8 < jb.Kpad && (n0 + rn) < jb.nrows){
      u16x8 o;
      #pragma unroll
      for (int q = 0; q < 8; ++q) o[q] = f2bf(t[c8 + q][rn]);
      *(u16x8*)(jb.BT + (size_t)(n0 + rn) * jb.Kpad + k0 + c8) = o;
    }
  }
}

// ---------------- projection GEMM: A0[1024][1024] x BTp[384][1024]^T -------
__global__ __launch_bounds__(512)
void k_proj_gemm(const u16* __restrict__ A, const u16* __restrict__ BT,
                 const float* __restrict__ bc,
                 u16* __restrict__ A1, u16* __restrict__ A2,
                 u16* __restrict__ A3, float* __restrict__ cl)
{
  constexpr int BK = 64, K = 1024;
  __shared__ u16 As[256 * BK];
  __shared__ u16 Bs[128 * BK];
  const int tid  = threadIdx.x;
  const int lane = tid & 63, wid = tid >> 6;
  const int wm = wid & 3, wn = wid >> 2;
  const int l15 = lane & 15, l4 = lane >> 4;
  const int m0 = blockIdx.y * 256;
  const int n0 = blockIdx.x * 128;

  f32x4 acc[4][4];
  #pragma unroll
  for (int m = 0; m < 4; ++m)
    #pragma unroll
    for (int n = 0; n < 4; ++n){ acc[m][n].x=0.f; acc[m][n].y=0.f; acc[m][n].z=0.f; acc[m][n].w=0.f; }

  for (int kt = 0; kt < K / BK; ++kt){
    #pragma unroll
    for (int i = 0; i < 4; ++i){
      int c = wid * 4 + i;
      int row = c * 8 + lane / 8, kb = lane % 8;
      glds16((const char*)(A + (size_t)(m0 + row) * K + kt * BK) + kb * 16,
             (char*)As + c * 1024);
    }
    #pragma unroll
    for (int i = 0; i < 2; ++i){
      int c = wid * 2 + i;
      int row = c * 8 + lane / 8, kb = lane % 8;
      glds16((const char*)(BT + (size_t)(n0 + row) * K + kt * BK) + kb * 16,
             (char*)Bs + c * 1024);
    }
    __syncthreads();
    #pragma unroll
    for (int ks = 0; ks < 2; ++ks){
      bf16x8 af[4], bfr[4];
      #pragma unroll
      for (int m = 0; m < 4; ++m)
        af[m] = *(const bf16x8*)((const char*)As + (wm*64 + m*16 + l15) * (BK*2) + ks*64 + l4*16);
      #pragma unroll
      for (int n = 0; n < 4; ++n)
        bfr[n] = *(const bf16x8*)((const char*)Bs + (wn*64 + n*16 + l15) * (BK*2) + ks*64 + l4*16);
      #pragma unroll
      for (int m = 0; m < 4; ++m)
        #pragma unroll
        for (int n = 0; n < 4; ++n)
          acc[m][n] = __builtin_amdgcn_mfma_f32_16x16x32_bf16(af[m], bfr[n], acc[m][n], 0, 0, 0);
    }
    __syncthreads();
  }
  #pragma unroll
  for (int m = 0; m < 4; ++m)
    #pragma unroll
    for (int n = 0; n < 4; ++n)
      #pragma unroll
      for (int q = 0; q < 4; ++q){
        int c = n0 + wn*64 + n*16 + l15;
        int r = m0 + wm*64 + m*16 + l4*4 + q;
        float v = acc[m][n][q];
        if (c < 256)      A1[(size_t)r*256 + c] = f2bf(v);
        else if (c < 320) A2[(size_t)r*64 + (c-256)] = f2bf(v);
        else if (c < 336){ A3[(size_t)r*32 + (c-320)] = f2bf(v);
                           A3[(size_t)r*32 + (c-320) + 16] = 0; }
        else if (c < 339) cl[(size_t)r*3 + (c-336)] = v + bc[c-336];
      }
}

// ---------------- head GEMM: triple-buffered counted-vmcnt pipeline --------
// BM=256 BN=128 BK=64, 512 thr (wm in {0,1} x wn in {0..3}); wave m-frags are
// interleaved 16-row strips so phase p consumes exactly A rows [64p,64p+64).
// 3 LDS slots; while computing tile t, stage tile t+2 into slot (t+2)%3
// (holds tile t-1, fully consumed). vmcnt(6) once per tile = 3 stage-units
// in flight. Raw s_barrier (no __syncthreads vmcnt(0) auto-drain).
template<int K, int T>
__global__ __launch_bounds__(512)
void k_gemm_lse8(const u16* __restrict__ A, const u16* __restrict__ BT,
                 const float* __restrict__ bias, int N,
                 MS* __restrict__ P, int ntiles,
                 const int* __restrict__ tgt_rel, float* __restrict__ tl)
{
  __shared__ u16 sm[3 * 24576];        // slot: A 32KB + B 16KB = 48KB
  __shared__ float redm[4][256];
  __shared__ float reds[4][256];

  const int tid  = threadIdx.x;
  const int lane = tid & 63, wid = tid >> 6;
  const int wm = wid & 1, wn = wid >> 1;
  const int l15 = lane & 15, l4 = lane >> 4;
  const int srow = tid >> 3, schk = tid & 7;

  // T1 bijective XCD swizzle (m204); consecutive swz = same col-tile chunk
  const int nwg = gridDim.x;
  int qq = nwg >> 3, rr = nwg & 7;
  int xcd = blockIdx.x & 7, ii = blockIdx.x >> 3;
  int swz = (xcd < rr ? xcd*(qq+1) : rr*(qq+1) + (xcd-rr)*qq) + ii;
  const int cb = swz >> 2, rb = swz & 3;
  const int m0 = rb * 256, n0 = cb * 128;

  auto stageA = [&](int kt, int rowbase, int slot){
    #pragma unroll
    for (int h = 0; h < 2; ++h){
      int r = rowbase + h*64 + srow;
      glds16((const char*)(A + (size_t)(m0 + r)*K + kt*64) + ((schk ^ (r & 7))*16),
             (char*)sm + slot*49152 + r*128 + schk*16);
    }
  };
  auto stageB = [&](int kt, int slot){
    #pragma unroll
    for (int h = 0; h < 2; ++h){
      int r = h*64 + srow;
      glds16((const char*)(BT + (size_t)(n0 + r)*K + kt*64) + ((schk ^ (r & 7))*16),
             (char*)sm + slot*49152 + 32768 + r*128 + schk*16);
    }
  };

  f32x4 acc[8][2];
  #pragma unroll
  for (int m = 0; m < 8; ++m)
    #pragma unroll
    for (int n = 0; n < 2; ++n){ acc[m][n].x=0.f; acc[m][n].y=0.f; acc[m][n].z=0.f; acc[m][n].w=0.f; }

  // prologue: stage tiles 0,1
  stageB(0, 0); stageA(0, 0, 0); stageA(0, 128, 0);
  stageB(1, 1); stageA(1, 0, 1); stageA(1, 128, 1);
  asm volatile("s_waitcnt vmcnt(6)" ::: "memory");
  __builtin_amdgcn_s_barrier();
  __builtin_amdgcn_sched_barrier(0);

  bf16x8 bfr[2][2];
  for (int t = 0; t < T; ++t){
    const int slot = t % 3;
    const char* As = (const char*)sm + slot*49152;
    const char* Bs = As + 32768;
    const int ps = (t + 2) % 3;
    const bool pf = (t + 2) < T;
    #pragma unroll
    for (int p = 0; p < 4; ++p){
      if (p == 0){
        #pragma unroll
        for (int n = 0; n < 2; ++n)
          #pragma unroll
          for (int ks = 0; ks < 2; ++ks){
            int r = wn*32 + n*16 + l15;
            bfr[n][ks] = *(const bf16x8*)(Bs + r*128 + (((ks*4 + l4) ^ (r & 7))*16));
          }
      }
      bf16x8 af[2][2];
      #pragma unroll
      for (int mm = 0; mm < 2; ++mm)
        #pragma unroll
        for (int ks = 0; ks < 2; ++ks){
          int r = (2*p + mm)*32 + wm*16 + l15;
          af[mm][ks] = *(const bf16x8*)(As + r*128 + (((ks*4 + l4) ^ (r & 7))*16));
        }
      if (pf){
        if (p == 0)      stageB(t+2, ps);
        else if (p == 1) stageA(t+2, 0, ps);
        else if (p == 2) stageA(t+2, 128, ps);
      }
      __builtin_amdgcn_s_barrier();            // pre-MFMA lockstep
      __builtin_amdgcn_s_setprio(1);
      #pragma unroll
      for (int mm = 0; mm < 2; ++mm)
        #pragma unroll
        for (int n = 0; n < 2; ++n)
          #pragma unroll
          for (int ks = 0; ks < 2; ++ks)
            acc[2*p+mm][n] = __builtin_amdgcn_mfma_f32_16x16x32_bf16(
                af[mm][ks], bfr[n][ks], acc[2*p+mm][n], 0, 0, 0);
      __builtin_amdgcn_s_setprio(0);
      if (p == 3){                              // tile boundary: counted wait
        if (pf) asm volatile("s_waitcnt vmcnt(6)" ::: "memory");
        else    asm volatile("s_waitcnt vmcnt(0)" ::: "memory");
      }
      __builtin_amdgcn_s_barrier();
      __builtin_amdgcn_sched_barrier(0);
    }
  }

  // ---- epilogue ----
  float bv[2]; bool val[2];
  #pragma unroll
  for (int n = 0; n < 2; ++n){
    int col = n0 + wn*32 + n*16 + l15;
    val[n] = col < N;
    bv[n] = val[n] ? bias[col] : 0.f;
  }
  // target-logit extraction (unique writer: tr in [n0, n0+128))
  #pragma unroll
  for (int m = 0; m < 8; ++m)
    #pragma unroll
    for (int q = 0; q < 4; ++q){
      int row = m0 + m*32 + wm*16 + l4*4 + q;
      int tr = tgt_rel[row];
      if (tr >= 0){
        #pragma unroll
        for (int n = 0; n < 2; ++n){
          int col = n0 + wn*32 + n*16 + l15;
          if (tr == col) tl[row] = acc[m][n][q] + bv[n];
        }
      }
    }
  // merged single-pass (M,S) reduce
  #pragma unroll
  for (int m = 0; m < 8; ++m)
    #pragma unroll
    for (int q = 0; q < 4; ++q){
      float Ml = -1e30f, Sl = 0.f;
      #pragma unroll
      for (int n = 0; n < 2; ++n)
        if (val[n]) Ml = fmaxf(Ml, acc[m][n][q] + bv[n]);
      #pragma unroll
      for (int n = 0; n < 2; ++n)
        if (val[n]) Sl += __expf(acc[m][n][q] + bv[n] - Ml);
      #pragma unroll
      for (int d = 1; d < 16; d <<= 1){
        float m2 = __shfl_xor(Ml, d), s2 = __shfl_xor(Sl, d);
        lse_merge(Ml, Sl, m2, s2);
      }
      if (l15 == 0){
        int lrow = m*32 + wm*16 + l4*4 + q;
        redm[wn][lrow] = Ml; reds[wn][lrow] = Sl;
      }
    }
  __syncthreads();
  if (wn == 0 && l15 == 0){
    #pragma unroll
    for (int m = 0; m < 8; ++m)
      #pragma unroll
      for (int q = 0; q < 4; ++q){
        int lrow = m*32 + wm*16 + l4*4 + q;
        float M = -1e30f, S = 0.f;
        #pragma unroll
        for (int w = 0; w < 4; ++w) lse_merge(M, S, redm[w][lrow], reds[w][lrow]);
        MS r; r.m = M; r.s = S;
        P[(size_t)(m0 + lrow) * ntiles + cb] = r;
      }
  }
}

// ---------------- tail GEMM + partial LSE (2-barrier structure) ----------
template<int BK>
__global__ __launch_bounds__(256)
void k_gemm_lse(const u16* __restrict__ A, const u16* __restrict__ BT,
                const float* __restrict__ bias, int K, int N,
                MS* __restrict__ P, int ntiles,
                const int* __restrict__ cntp, int bucket,
                const int* __restrict__ tgt_rel, const int* __restrict__ rowmap,
                float* __restrict__ tl)
{
  constexpr int BM = 128, BN = 128;
  constexpr int CH  = BK / 8;
  constexpr int LPR = CH;
  constexpr int RPC = 64 / LPR;
  constexpr int NC  = BM * BK * 2 / 1024;
  constexpr int CPW = NC / 4;
  if (cntp && (int)(blockIdx.y * BM) >= cntp[bucket]) return;
  __shared__ u16 As[BM * BK];
  __shared__ u16 Bs[BN * BK];
  __shared__ float redm[2][BM];
  __shared__ float reds[2][BM];

  const int tid  = threadIdx.x;
  const int lane = tid & 63, wid = tid >> 6;
  const int wm = wid & 1, wn = wid >> 1;
  const int l15 = lane & 15, l4 = lane >> 4;
  const int m0 = blockIdx.y * BM;
  const int n0 = blockIdx.x * BN;
  const int srow = lane / LPR;
  const int skb  = lane % LPR;

  f32x4 acc[4][4];
  #pragma unroll
  for (int m = 0; m < 4; ++m)
    #pragma unroll
    for (int n = 0; n < 4; ++n){ acc[m][n].x=0.f; acc[m][n].y=0.f; acc[m][n].z=0.f; acc[m][n].w=0.f; }

  const int ksteps = K / BK;
  for (int kt = 0; kt < ksteps; ++kt){
    #pragma unroll
    for (int i = 0; i < CPW; ++i){
      int c = wid * CPW + i;
      int row = c * RPC + srow;
      int kbs = skb ^ (row & (CH - 1));
      glds16((const char*)(A + (size_t)(m0 + row) * K + kt * BK) + kbs * 16,
             (char*)As + c * 1024);
    }
    #pragma unroll
    for (int i = 0; i < CPW; ++i){
      int c = wid * CPW + i;
      int row = c * RPC + srow;
      int kbs = skb ^ (row & (CH - 1));
      glds16((const char*)(BT + (size_t)(n0 + row) * K + kt * BK) + kbs * 16,
             (char*)Bs + c * 1024);
    }
    __syncthreads();
    #pragma unroll
    for (int ks = 0; ks < BK / 32; ++ks){
      bf16x8 af[4], bfr[4];
      #pragma unroll
      for (int m = 0; m < 4; ++m){
        int r = wm*64 + m*16 + l15;
        af[m] = *(const bf16x8*)((const char*)As + r*(BK*2) + (((ks*4 + l4) ^ (r & (CH-1))) * 16));
      }
      #pragma unroll
      for (int n = 0; n < 4; ++n){
        int r = wn*64 + n*16 + l15;
        bfr[n] = *(const bf16x8*)((const char*)Bs + r*(BK*2) + (((ks*4 + l4) ^ (r & (CH-1))) * 16));
      }
      #pragma unroll
      for (int m = 0; m < 4; ++m)
        #pragma unroll
        for (int n = 0; n < 4; ++n)
          acc[m][n] = __builtin_amdgcn_mfma_f32_16x16x32_bf16(af[m], bfr[n], acc[m][n], 0, 0, 0);
    }
    __syncthreads();
  }

  // ---- epilogue ----
  float bv[4]; bool val[4];
  #pragma unroll
  for (int n = 0; n < 4; ++n){
    int col = n0 + wn*64 + n*16 + l15;
    val[n] = col < N;
    bv[n] = val[n] ? bias[col] : 0.f;
  }
  #pragma unroll
  for (int m = 0; m < 4; ++m)
    #pragma unroll
    for (int q = 0; q < 4; ++q){
      int row = m0 + wm*64 + m*16 + l4*4 + q;
      int tr = tgt_rel[row];
      if (tr >= 0){
        #pragma unroll
        for (int n = 0; n < 4; ++n){
          int col = n0 + wn*64 + n*16 + l15;
          if (tr == col)
            tl[rowmap ? rowmap[row] : row] = acc[m][n][q] + bv[n];
        }
      }
    }
  // merged single-pass (M,S) reduce
  #pragma unroll
  for (int m = 0; m < 4; ++m)
    #pragma unroll
    for (int q = 0; q < 4; ++q){
      float Ml = -1e30f, Sl = 0.f;
      #pragma unroll
      for (int n = 0; n < 4; ++n)
        if (val[n]) Ml = fmaxf(Ml, acc[m][n][q] + bv[n]);
      #pragma unroll
      for (int n = 0; n < 4; ++n)
        if (val[n]) Sl += __expf(acc[m][n][q] + bv[n] - Ml);
      #pragma unroll
      for (int d = 1; d < 16; d <<= 1){
        float m2 = __shfl_xor(Ml, d), s2 = __shfl_xor(Sl, d);
        lse_merge(Ml, Sl, m2, s2);
      }
      if (l15 == 0){
        int lrow = wm*64 + m*16 + l4*4 + q;
        redm[wn][lrow] = Ml; reds[wn][lrow] = Sl;
      }
    }
  __syncthreads();
  if (wn == 0 && l15 == 0){
    #pragma unroll
    for (int m = 0; m < 4; ++m)
      #pragma unroll
      for (int q = 0; q < 4; ++q){
        int lrow = wm*64 + m*16 + l4*4 + q;
        float M = redm[0][lrow], S = reds[0][lrow];
        lse_merge(M, S, redm[1][lrow], reds[1][lrow]);
        MS r; r.m = M; r.s = S;
        P[(size_t)(m0 + lrow) * ntiles + blockIdx.x] = r;
      }
  }
}

// ---------------- final combine ----------------
__global__ void k_finalize(const int* __restrict__ tgt, const MS* __restrict__ P,
                           const float* __restrict__ cl, const float* __restrict__ tl,
                           const int* __restrict__ pos, float* __restrict__ out)
{
  const int NT0 = 157, NT1 = 313, NT2 = 938, NT3 = 686;
  int n = blockIdx.x * 4 + (threadIdx.x >> 6);
  int lane = threadIdx.x & 63;
  int t = tgt[n];

  float m = -1e30f, s = 0.f;
  const MS* p0 = P + (size_t)n * NT0;
  for (int i = lane; i < NT0; i += 64){ MS v = p0[i]; lse_merge(m, s, v.m, v.s); }
  if (lane < 3) lse_merge(m, s, cl[n*3 + lane], 1.f);
  #pragma unroll
  for (int d = 1; d < 64; d <<= 1){
    float m2 = __shfl_xor(m, d), s2 = __shfl_xor(s, d);
    lse_merge(m, s, m2, s2);
  }
  float lse_head = m + logf(s);

  float nll;
  if (t < 20000){
    nll = lse_head - tl[n];
  } else {
    int seg, nt; size_t base;
    if      (t <  60000){ seg = 1; nt = NT1; base = (size_t)1024 * NT0; }
    else if (t < 180000){ seg = 2; nt = NT2; base = (size_t)1024 * (NT0 + NT1); }
    else                { seg = 3; nt = NT3; base = (size_t)1024 * (NT0 + NT1 + NT2); }
    float m2 = -1e30f, s2 = 0.f;
    const MS* ps = P + base + (size_t)pos[n] * nt;
    for (int i = lane; i < nt; i += 64){ MS v = ps[i]; lse_merge(m2, s2, v.m, v.s); }
    #pragma unroll
    for (int d = 1; d < 64; d <<= 1){
      float mm = __shfl_xor(m2, d), ss = __shfl_xor(s2, d);
      lse_merge(m2, s2, mm, ss);
    }
    float lse_t = m2 + logf(s2);
    // reference quirk: bucket i uses head_lp[:, -i] == cluster logit index 3-i
    nll = lse_head - cl[n*3 + (3 - seg)] + lse_t - tl[n];
  }
  if (lane == 0) out[n] = nll;
}

// ---------------------------------------------------------------------------
extern "C" void kernel_launch(void* const* d_in, const int* in_sizes, int n_in,
                              void* d_out, int out_size, void* d_ws, size_t ws_size,
                              hipStream_t stream)
{
  const float* hidden = (const float*)d_in[0];
  const int*   target = (const int*)d_in[1];
  const float* W_head = (const float*)d_in[2];
  const float* b_head = (const float*)d_in[3];
  const float* W_clu  = (const float*)d_in[4];
  const float* b_clu  = (const float*)d_in[5];
  const float* W_p1   = (const float*)d_in[6];
  const float* W_t1   = (const float*)d_in[7];
  const float* b_t1   = (const float*)d_in[8];
  const float* W_p2   = (const float*)d_in[9];
  const float* W_t2   = (const float*)d_in[10];
  const float* b_t2   = (const float*)d_in[11];
  const float* W_p3   = (const float*)d_in[12];
  const float* W_t3   = (const float*)d_in[13];
  const float* b_t3   = (const float*)d_in[14];
  float* out = (float*)d_out;

  char* ws = (char*)d_ws;
  u16*   A0  = (u16*)(ws + 0);
  u16*   A1  = (u16*)(ws + 2097152);
  u16*   A2  = (u16*)(ws + 2621440);
  u16*   A3  = (u16*)(ws + 2752512);
  float* cl  = (float*)(ws + 2818048);
  float* tl  = (float*)(ws + 2834432);
  MS*    P   = (MS*)(ws + 2838528);
  u16*   BTp = (u16*)(ws + 2838528);    // proj weights; dead before P is live
  u16*   BTh = (u16*)(ws + 19992576);   // head BT [20096][1024]
  int*   cnt  = (int*)(ws + 61149184);
  int*   idx1 = (int*)(ws + 61149440);
  int*   idx2 = (int*)(ws + 61153536);
  int*   idx3 = (int*)(ws + 61157632);
  int*   pos  = (int*)(ws + 61161728);
  u16*   A1c  = (u16*)(ws + 61165824);
  u16*   A2c  = (u16*)(ws + 61690112);
  u16*   A3c  = (u16*)(ws + 61821184);
  int*   tr0  = (int*)(ws + 61886720);
  int*   tr1  = (int*)(ws + 61890816);
  int*   tr2  = (int*)(ws + 61894912);
  int*   tr3  = (int*)(ws + 61899008);
  u16*   BT1  = (u16*)(ws + 61903104);  // [40064][256]
  u16*   BT2  = (u16*)(ws + 82415872);  // [120064][64]
  u16*   BT3  = (u16*)(ws + 97784064);  // [87808][32]
  const size_t needA = 103403776;
  const bool bigws = ws_size >= needA;

  const size_t P1 = (size_t)1024 * 157;
  const size_t P2 = (size_t)1024 * (157 + 313);
  const size_t P3 = (size_t)1024 * (157 + 313 + 938);

  k_cvt_hidden<<<512, 256, 0, stream>>>(hidden, A0, cnt, tr0);
  k_compact<<<4, 256, 0, stream>>>(target, cnt, idx1, idx2, idx3, pos,
                                   tr0, tr1, tr2, tr3);

  TJobs tj{}; int nb = 0;
  auto add = [&](const float* W, u16* B, int K, int N, int Kpad, int nrows){
    int nx = (nrows + 63) / 64;
    int ny = (Kpad + 63) / 64;
    tj.j[tj.nj++] = TJob{W, B, K, N, Kpad, nrows, nx, nb};
    nb += nx * ny;
  };
  add(W_p1, BTp, 1024, 256, 1024, 256);
  add(W_p2, BTp + (size_t)256*1024, 1024, 64, 1024, 64);
  add(W_p3, BTp + (size_t)320*1024, 1024, 16, 1024, 16);
  add(W_clu, BTp + (size_t)336*1024, 1024, 3, 1024, 64);
  add(W_head, BTh, 1024, 20000, 1024, 20096);
  if (bigws){
    add(W_t1, BT1, 256, 40000, 256, 40064);
    add(W_t2, BT2, 64, 120000, 64, 120064);
    add(W_t3, BT3, 16, 87735, 32, 87808);
  }
  k_transpose_multi<<<nb, 256, 0, stream>>>(tj);

  k_proj_gemm<<<dim3(3, 4), 512, 0, stream>>>(A0, BTp, b_clu, A1, A2, A3, cl);
  k_gather<<<176, 256, 0, stream>>>(cnt, idx1, idx2, idx3, A1, A2, A3, A1c, A2c, A3c);

  // head: pipelined kernel, grid 157 col-tiles x 4 row-tiles = 628 (1D)
  k_gemm_lse8<1024, 16><<<628, 512, 0, stream>>>(A0, BTh, b_head, 20000,
      P, 157, tr0, tl);

  if (bigws){
    k_gemm_lse<64><<<dim3(313, 8), 256, 0, stream>>>(A1c, BT1, b_t1, 256, 40000,
        P + P1, 313, cnt, 0, tr1, idx1, tl);
    k_gemm_lse<64><<<dim3(938, 8), 256, 0, stream>>>(A2c, BT2, b_t2, 64, 120000,
        P + P2, 938, cnt, 1, tr2, idx2, tl);
    k_gemm_lse<32><<<dim3(686, 8), 256, 0, stream>>>(A3c, BT3, b_t3, 32, 87735,
        P + P3, 686, cnt, 2, tr3, idx3, tl);
  } else {
    TJobs s1{}; s1.nj = 1; s1.j[0] = TJob{W_t1, BTh, 256, 40000, 256, 40064, 626, 0};
    k_transpose_multi<<<626*4, 256, 0, stream>>>(s1);
    k_gemm_lse<64><<<dim3(313, 8), 256, 0, stream>>>(A1c, BTh, b_t1, 256, 40000,
        P + P1, 313, cnt, 0, tr1, idx1, tl);
    TJobs s2{}; s2.nj = 1; s2.j[0] = TJob{W_t2, BTh, 64, 120000, 64, 120064, 1876, 0};
    k_transpose_multi<<<1876, 256, 0, stream>>>(s2);
    k_gemm_lse<64><<<dim3(938, 8), 256, 0, stream>>>(A2c, BTh, b_t2, 64, 120000,
        P + P2, 938, cnt, 1, tr2, idx2, tl);
    TJobs s3{}; s3.nj = 1; s3.j[0] = TJob{W_t3, BTh, 16, 87735, 32, 87808, 1372, 0};
    k_transpose_multi<<<1372, 256, 0, stream>>>(s3);
    k_gemm_lse<32><<<dim3(686, 8), 256, 0, stream>>>(A3c, BTh, b_t3, 32, 87735,
        P + P3, 686, cnt, 2, tr3, idx3, tl);
  }

  k_finalize<<<256, 256, 0, stream>>>(target, P, cl, tl, pos, out);
}